// Round 5
// baseline (399.172 us; speedup 1.0000x reference)
//
#include <hip/hip_runtime.h>

#define NNODES 50000
#define NEDGES 800000
#define NPAD   50176          // 196*256, padded bin count for the scan
#define NTILE_E (NEDGES / 16) // 50000 edge tiles
#define NTILE_N (NNODES / 16) // 3125 node tiles

typedef __attribute__((ext_vector_type(8))) short bf16x8;   // 8 bf16 = 4 VGPRs
typedef __attribute__((ext_vector_type(4))) float f32x4;

union ABu { bf16x8 v; uint4 u; };

// tanh(x) = 1 - 2/(exp(2x)+1); saturates cleanly, no NaN.
__device__ __forceinline__ float fast_tanh(float x) {
    float e = __expf(2.0f * x);
    return 1.0f - 2.0f * __builtin_amdgcn_rcpf(e + 1.0f);
}

// RNE pack two f32 -> bf16x2
__device__ __forceinline__ unsigned pk_rne(float x, float y) {
    unsigned a = __float_as_uint(x), b = __float_as_uint(y);
    a = (a + 0x7fffu + ((a >> 16) & 1u)) >> 16;
    b = (b + 0x7fffu + ((b >> 16) & 1u)) >> 16;
    return a | (b << 16);
}
// truncating pack (1 v_perm): dst = {a[31:16], b[31:16]}
__device__ __forceinline__ unsigned pk_tr(float a, float b) {
    return __builtin_amdgcn_perm(__float_as_uint(b), __float_as_uint(a), 0x07060302);
}
__device__ __forceinline__ float bf16_lo(unsigned u) { return __uint_as_float(u << 16); }
__device__ __forceinline__ float bf16_hi(unsigned u) { return __uint_as_float(u & 0xffff0000u); }

// A-fragment (lane holds A[m=lane&15][k=quad*8+j]) from 8 consecutive f32
__device__ __forceinline__ ABu make_afrag(const float* p) {
    float4 a = ((const float4*)p)[0];
    float4 b = ((const float4*)p)[1];
    ABu r;
    r.u.x = pk_tr(a.x, a.y); r.u.y = pk_tr(a.z, a.w);
    r.u.z = pk_tr(b.x, b.y); r.u.w = pk_tr(b.z, b.w);
    return r;
}

// B-fragment from bf16x2-packed LDS: wl_u[kp*LDN + n], kp = k/2
template <int LDN>
__device__ __forceinline__ ABu make_bfrag_u(const unsigned* wp) {
    ABu r;
    r.u.x = wp[0 * LDN]; r.u.y = wp[1 * LDN];
    r.u.z = wp[2 * LDN]; r.u.w = wp[3 * LDN];
    return r;
}

// stage f32 weight [K][N] -> packed bf16 pairs [K/2][N] in LDS
template <int KH, int N>
__device__ __forceinline__ void stage_w(const float* __restrict__ w, unsigned* wl_u) {
    for (int i = threadIdx.x; i < KH * N; i += 256) {
        const int kp = i / N, n = i % N;  // N = 32/64 -> shifts
        wl_u[i] = pk_rne(w[(2 * kp) * N + n], w[(2 * kp + 1) * N + n]);
    }
}

#define MFMA(a, b, c) __builtin_amdgcn_mfma_f32_16x16x32_bf16((a).v, (b).v, (c), 0, 0, 0)

// ---------- K0: dst histogram + per-edge rank within dst segment ----------
__global__ __launch_bounds__(256) void hist_kernel(const int* __restrict__ dst_idx,
                                                   int* __restrict__ cnt,
                                                   int* __restrict__ rank) {
    const int base = (blockIdx.x * 256 + threadIdx.x) * 4;
    if (base + 4 <= NEDGES) {
        int4 d = *(const int4*)(dst_idx + base);
        int4 r;
        r.x = atomicAdd(&cnt[d.x], 1);
        r.y = atomicAdd(&cnt[d.y], 1);
        r.z = atomicAdd(&cnt[d.z], 1);
        r.w = atomicAdd(&cnt[d.w], 1);
        *(int4*)(rank + base) = r;
    } else {
        for (int i = base; i < NEDGES; ++i) rank[i] = atomicAdd(&cnt[dst_idx[i]], 1);
    }
}

// ---------- K2/K3/K4: exclusive scan of 50176 bins ----------
__global__ __launch_bounds__(256) void scan1(const int* __restrict__ cnt,
                                             int* __restrict__ off,
                                             int* __restrict__ btot) {
    __shared__ int s[256];
    const int tid = threadIdx.x;
    const int g = blockIdx.x * 256 + tid;
    const int own = cnt[g];
    s[tid] = own;
    __syncthreads();
    for (int o = 1; o < 256; o <<= 1) {
        int v = (tid >= o) ? s[tid - o] : 0;
        __syncthreads();
        s[tid] += v;
        __syncthreads();
    }
    off[g] = s[tid] - own;
    if (tid == 255) btot[blockIdx.x] = s[255];
}

__global__ __launch_bounds__(256) void scan2(int* __restrict__ btot) {
    __shared__ int s[256];
    const int tid = threadIdx.x;
    const int own = btot[tid];
    s[tid] = own;
    __syncthreads();
    for (int o = 1; o < 256; o <<= 1) {
        int v = (tid >= o) ? s[tid - o] : 0;
        __syncthreads();
        s[tid] += v;
        __syncthreads();
    }
    btot[tid] = s[tid] - own;
}

__global__ __launch_bounds__(256) void scan3(int* __restrict__ off,
                                             const int* __restrict__ btot) {
    const int g = blockIdx.x * 256 + threadIdx.x;
    off[g] += btot[blockIdx.x];
}

// ---------- K5: fold rank -> absolute row: rank[e] += off[dst[e]] (in place) ----------
__global__ __launch_bounds__(256) void rows_kernel(const int* __restrict__ dst_idx,
                                                   const int* __restrict__ off,
                                                   int* __restrict__ rank) {
    const int base = (blockIdx.x * 256 + threadIdx.x) * 4;
    if (base + 4 <= NEDGES) {
        int4 d = *(const int4*)(dst_idx + base);
        int4 r = *(const int4*)(rank + base);
        r.x += off[d.x];
        r.y += off[d.y];
        r.z += off[d.z];
        r.w += off[d.w];
        *(int4*)(rank + base) = r;
    } else {
        for (int i = base; i < NEDGES; ++i) rank[i] += off[dst_idx[i]];
    }
}

// ---------- proj2: fused per-node GEMM: projm = feat@Wm + bm ; p1 = feat@We1 + be ----------
// projm storage NT=4 swizzle: projm[n*64 + col*4 + nt] = logical col nt*16+col.
// p1 storage NT=2 swizzle:    p1[n*32 + col*2 + nt]    = logical col nt*16+col.
__global__ __launch_bounds__(256) void proj2_kernel(
    const float* __restrict__ feat,
    const float* __restrict__ w_m, const float* __restrict__ b_m,
    const float* __restrict__ w_e, const float* __restrict__ b_e,
    float* __restrict__ projm, float* __restrict__ p1) {
    __shared__ __align__(16) unsigned wlm[32 * 64];  // 8 KB
    __shared__ __align__(16) unsigned wle[32 * 32];  // 4 KB
    stage_w<32, 64>(w_m, wlm);
    stage_w<32, 32>(w_e, wle);
    __syncthreads();

    const int lane = threadIdx.x & 63, wave = threadIdx.x >> 6;
    const int col = lane & 15, quad = lane >> 4;

    ABu bfm[2][4], bfe[2][2];
#pragma unroll
    for (int kc = 0; kc < 2; ++kc) {
#pragma unroll
        for (int nt = 0; nt < 4; ++nt)
            bfm[kc][nt] = make_bfrag_u<64>(&wlm[(kc * 16 + (quad << 2)) * 64 + nt * 16 + col]);
#pragma unroll
        for (int nt = 0; nt < 2; ++nt)
            bfe[kc][nt] = make_bfrag_u<32>(&wle[(kc * 16 + (quad << 2)) * 32 + nt * 16 + col]);
    }

    float bim[4], bie[2];
#pragma unroll
    for (int nt = 0; nt < 4; ++nt) bim[nt] = b_m[nt * 16 + col];
#pragma unroll
    for (int nt = 0; nt < 2; ++nt) bie[nt] = b_e[nt * 16 + col];

    const int nw = gridDim.x << 2;
    for (int t = (blockIdx.x << 2) + wave; t < NTILE_N; t += nw) {
        const int n0 = t << 4;
        const int n = n0 + col;
        ABu a0 = make_afrag(feat + (size_t)n * 64 + (quad << 3));
        ABu a1 = make_afrag(feat + (size_t)n * 64 + 32 + (quad << 3));

        f32x4 accm[4], acce[2];
#pragma unroll
        for (int nt = 0; nt < 4; ++nt)
            accm[nt] = (f32x4){bim[nt], bim[nt], bim[nt], bim[nt]};
#pragma unroll
        for (int nt = 0; nt < 2; ++nt)
            acce[nt] = (f32x4){bie[nt], bie[nt], bie[nt], bie[nt]};
#pragma unroll
        for (int nt = 0; nt < 4; ++nt) {
            accm[nt] = MFMA(a0, bfm[0][nt], accm[nt]);
            accm[nt] = MFMA(a1, bfm[1][nt], accm[nt]);
        }
#pragma unroll
        for (int nt = 0; nt < 2; ++nt) {
            acce[nt] = MFMA(a0, bfe[0][nt], acce[nt]);
            acce[nt] = MFMA(a1, bfe[1][nt], acce[nt]);
        }
#pragma unroll
        for (int i = 0; i < 4; ++i) {
            const int nr = n0 + (quad << 2) + i;
            float4 om = {accm[0][i], accm[1][i], accm[2][i], accm[3][i]};
            *(float4*)(projm + (size_t)nr * 64 + (col << 2)) = om;
            float2 oe = {acce[0][i], acce[1][i]};
            *(float2*)(p1 + (size_t)nr * 32 + (col << 1)) = oe;
        }
    }
}

// ---------- proj: per-node streaming GEMM  out = in @ W (+bias) (used for p2) ----------
template <int KC, int NT>
__global__ __launch_bounds__(256) void proj_kernel(
    const float* __restrict__ in, const float* __restrict__ w,
    const float* __restrict__ bias, float* __restrict__ out) {
    constexpr int N = NT * 16;
    constexpr int K = KC * 32;
    __shared__ __align__(16) unsigned wl[(K / 2) * N];
    stage_w<K / 2, N>(w, wl);
    __syncthreads();

    const int lane = threadIdx.x & 63, wave = threadIdx.x >> 6;
    const int col = lane & 15, quad = lane >> 4;

    ABu bf[KC][NT];
#pragma unroll
    for (int kc = 0; kc < KC; ++kc)
#pragma unroll
        for (int nt = 0; nt < NT; ++nt)
            bf[kc][nt] = make_bfrag_u<N>(&wl[(kc * 16 + (quad << 2)) * N + nt * 16 + col]);

    float bi[NT];
#pragma unroll
    for (int nt = 0; nt < NT; ++nt) bi[nt] = bias ? bias[nt * 16 + col] : 0.f;

    const int nw = gridDim.x << 2;
    for (int t = (blockIdx.x << 2) + wave; t < NTILE_N; t += nw) {
        const int n0 = t << 4;
        const int n = n0 + col;
        ABu a[KC];
#pragma unroll
        for (int kc = 0; kc < KC; ++kc)
            a[kc] = make_afrag(in + (size_t)n * K + kc * 32 + (quad << 3));

        f32x4 acc[NT];
#pragma unroll
        for (int nt = 0; nt < NT; ++nt)
            acc[nt] = (f32x4){bi[nt], bi[nt], bi[nt], bi[nt]};
#pragma unroll
        for (int nt = 0; nt < NT; ++nt)
#pragma unroll
            for (int kc = 0; kc < KC; ++kc)
                acc[nt] = MFMA(a[kc], bf[kc][nt], acc[nt]);

#pragma unroll
        for (int i = 0; i < 4; ++i) {
            const int nr = n0 + (quad << 2) + i;
            if (NT == 4) {
                float4 o = {acc[0][i], acc[1][i], acc[2][i], acc[3][i]};
                *(float4*)(out + (size_t)nr * 64 + (col << 2)) = o;
            } else {
                float2 o = {acc[0][i], acc[1][i]};
                *(float2*)(out + (size_t)nr * 32 + (col << 1)) = o;
            }
        }
    }
}

// ---------- K1: message = tanh(projm[src] + ef @ W_bot) -> dst-sorted m  (+ q3 = ef@W3) ----------
// m storage (uint index s in [0,32) per edge): s = col*2 + w;
//   w=0 -> logical cols (col, col+16), w=1 -> (col+32, col+48)
// q3 storage: q3[e*16 + col] = pk(logical col, col+16) -- matches p1/p2 swizzle.
struct MsgBuf { ABu a2; float4 f4[4]; int4 rows; };

__device__ __forceinline__ void msg_load(
    int t, int col, int quad,
    const float* __restrict__ edge_feat, const float* __restrict__ projm,
    const int* __restrict__ src_idx, const int* __restrict__ rows, MsgBuf& b) {
    const int e0 = t << 4;
    const int4 s4 = *(const int4*)(src_idx + e0 + (quad << 2));
    b.rows = *(const int4*)(rows + e0 + (quad << 2));
    b.a2 = make_afrag(edge_feat + (size_t)(e0 + col) * 32 + (quad << 3));
    b.f4[0] = *(const float4*)(projm + (size_t)s4.x * 64 + (col << 2));
    b.f4[1] = *(const float4*)(projm + (size_t)s4.y * 64 + (col << 2));
    b.f4[2] = *(const float4*)(projm + (size_t)s4.z * 64 + (col << 2));
    b.f4[3] = *(const float4*)(projm + (size_t)s4.w * 64 + (col << 2));
}

template <bool WQ3>
__device__ __forceinline__ void msg_comp(
    int t, int col, int quad, const ABu (&bf)[4], const ABu (&bf3)[2],
    const MsgBuf& b, unsigned* __restrict__ m_out, unsigned* __restrict__ q3_out) {
    f32x4 acc[4];
#pragma unroll
    for (int nt = 0; nt < 4; ++nt) acc[nt] = (f32x4){0.f, 0.f, 0.f, 0.f};
#pragma unroll
    for (int nt = 0; nt < 4; ++nt) acc[nt] = MFMA(b.a2, bf[nt], acc[nt]);
    const int rw[4] = {b.rows.x, b.rows.y, b.rows.z, b.rows.w};
#pragma unroll
    for (int i = 0; i < 4; ++i) {
        uint2 o;
        o.x = pk_rne(fast_tanh(acc[0][i] + b.f4[i].x), fast_tanh(acc[1][i] + b.f4[i].y));
        o.y = pk_rne(fast_tanh(acc[2][i] + b.f4[i].z), fast_tanh(acc[3][i] + b.f4[i].w));
        *(uint2*)(m_out + (size_t)rw[i] * 32 + (col << 1)) = o;  // 128B/quad contiguous
    }
    if (WQ3) {
        f32x4 a3[2];
#pragma unroll
        for (int nt = 0; nt < 2; ++nt) a3[nt] = (f32x4){0.f, 0.f, 0.f, 0.f};
#pragma unroll
        for (int nt = 0; nt < 2; ++nt) a3[nt] = MFMA(b.a2, bf3[nt], a3[nt]);
        const int e0 = t << 4;
#pragma unroll
        for (int i = 0; i < 4; ++i)
            q3_out[(size_t)(e0 + (quad << 2) + i) * 16 + col] = pk_rne(a3[0][i], a3[1][i]);
    }
}

template <bool WQ3>
__global__ __launch_bounds__(256) void msg_kernel(
    const float* __restrict__ edge_feat, const float* __restrict__ w_bot,
    const float* __restrict__ w3,
    const int* __restrict__ src_idx, const int* __restrict__ rows,
    const float* __restrict__ projm, unsigned* __restrict__ m_out,
    unsigned* __restrict__ q3_out) {
    __shared__ __align__(16) unsigned wl[16 * 64];   // 4 KB: W_bot rows 0..31 packed
    __shared__ __align__(16) unsigned wl3[16 * 32];  // 2 KB: W3 packed
    stage_w<16, 64>(w_bot, wl);
    if (WQ3) stage_w<16, 32>(w3, wl3);
    __syncthreads();

    const int lane = threadIdx.x & 63, wave = threadIdx.x >> 6;
    const int col = lane & 15, quad = lane >> 4;

    ABu bf[4], bf3[2];
#pragma unroll
    for (int nt = 0; nt < 4; ++nt)
        bf[nt] = make_bfrag_u<64>(&wl[(quad << 2) * 64 + nt * 16 + col]);
    if (WQ3) {
#pragma unroll
        for (int nt = 0; nt < 2; ++nt)
            bf3[nt] = make_bfrag_u<32>(&wl3[(quad << 2) * 32 + nt * 16 + col]);
    }

    const int nw = gridDim.x << 2;
    int t = (blockIdx.x << 2) + wave;
    if (t >= NTILE_E) return;
    MsgBuf A, B;
    msg_load(t, col, quad, edge_feat, projm, src_idx, rows, A);
    for (;;) {
        const int t2 = t + nw;
        if (t2 < NTILE_E)
            msg_load(t2, col, quad, edge_feat, projm, src_idx, rows, B);
        msg_comp<WQ3>(t, col, quad, bf, bf3, A, m_out, q3_out);
        if (t2 >= NTILE_E) return;
        const int t3 = t2 + nw;
        if (t3 < NTILE_E)
            msg_load(t3, col, quad, edge_feat, projm, src_idx, rows, A);
        msg_comp<WQ3>(t2, col, quad, bf, bf3, B, m_out, q3_out);
        if (t3 >= NTILE_E) return;
        t = t3;
    }
}

// ---------- K6: segmented mean -> neigh. m rows dst-sorted => streaming reads.
__global__ __launch_bounds__(256) void gather_kernel(
    const unsigned* __restrict__ m,
    const int* __restrict__ off /* exclusive starts */, const int* __restrict__ cnt,
    float* __restrict__ neigh) {
    const int wave = threadIdx.x >> 6;
    const int lane = threadIdx.x & 63;
    const int n = blockIdx.x * 4 + wave;
    if (n >= NNODES) return;
    const int c = cnt[n];
    const int o = off[n];
    const int q = lane & 7;   // uint4 index within 128B row
    const int g = lane >> 3;  // row group 0..7

    float s[8];
#pragma unroll
    for (int j = 0; j < 8; ++j) s[j] = 0.f;
    for (int r = g; r < c; r += 8) {
        const uint4 u = *(const uint4*)(m + (size_t)(o + r) * 32 + (q << 2));
        s[0] += bf16_lo(u.x); s[1] += bf16_hi(u.x);
        s[2] += bf16_lo(u.y); s[3] += bf16_hi(u.y);
        s[4] += bf16_lo(u.z); s[5] += bf16_hi(u.z);
        s[6] += bf16_lo(u.w); s[7] += bf16_hi(u.w);
    }
#pragma unroll
    for (int j = 0; j < 8; ++j) {
        s[j] += __shfl_xor(s[j], 8);
        s[j] += __shfl_xor(s[j], 16);
        s[j] += __shfl_xor(s[j], 32);
    }
    if (g == 0) {
        const float inv = __builtin_amdgcn_rcpf((float)max(c, 1));
        float4 o0 = {s[0] * inv, s[1] * inv, s[2] * inv, s[3] * inv};
        float4 o1 = {s[4] * inv, s[5] * inv, s[6] * inv, s[7] * inv};
        float* dst = neigh + (size_t)n * 64 + (q << 3);
        ((float4*)dst)[0] = o0;
        ((float4*)dst)[1] = o1;  // storage order, unswizzled in K7
    }
}

// storage k -> logical w_node row (undo the m/neigh swizzle) for k<64
__device__ __forceinline__ int mapk(int ks) {
    return ks < 64 ? ((ks >> 2) + ((ks >> 1) & 1) * 32 + (ks & 1) * 16) : ks;
}

// ---------- K7: node MLP (MFMA), T-loop, pre-packed swizzled weights ----------
__global__ __launch_bounds__(256) void node_update(
    const float* __restrict__ feat,
    const float* __restrict__ w_node, const float* __restrict__ b_node,
    float* __restrict__ h) {
    // wl[kp*64 + n] = pk(w_node[mapk(2kp)][n], w_node[mapk(2kp+1)][n])  (16 KB)
    __shared__ __align__(16) unsigned wl[64 * 64];
    for (int i = threadIdx.x; i < 64 * 64; i += 256) {
        const int kp = i >> 6, n = i & 63;
        wl[i] = pk_rne(w_node[mapk(2 * kp) * 64 + n], w_node[mapk(2 * kp + 1) * 64 + n]);
    }
    __syncthreads();

    const int lane = threadIdx.x & 63, wave = threadIdx.x >> 6;
    const int col = lane & 15, quad = lane >> 4;

    ABu bf[4][4];
#pragma unroll
    for (int kc = 0; kc < 4; ++kc)
#pragma unroll
        for (int nt = 0; nt < 4; ++nt)
            bf[kc][nt] = make_bfrag_u<64>(&wl[(kc * 16 + (quad << 2)) * 64 + nt * 16 + col]);

    float bias[4];
#pragma unroll
    for (int nt = 0; nt < 4; ++nt) bias[nt] = b_node[nt * 16 + col];

    const int nw = gridDim.x << 2;
    for (int t = (blockIdx.x << 2) + wave; t < NTILE_N; t += nw) {
        const int n0 = t << 4;
        const int n = n0 + col;
        ABu a0 = make_afrag(h + (size_t)n * 64 + quad * 8);  // neigh (storage order)
        ABu a1 = make_afrag(h + (size_t)n * 64 + 32 + quad * 8);
        ABu a2 = make_afrag(feat + (size_t)n * 64 + quad * 8);
        ABu a3 = make_afrag(feat + (size_t)n * 64 + 32 + quad * 8);

        f32x4 acc[4];
#pragma unroll
        for (int nt = 0; nt < 4; ++nt)
            acc[nt] = (f32x4){bias[nt], bias[nt], bias[nt], bias[nt]};
#pragma unroll
        for (int nt = 0; nt < 4; ++nt) {
            acc[nt] = MFMA(a0, bf[0][nt], acc[nt]);
            acc[nt] = MFMA(a1, bf[1][nt], acc[nt]);
            acc[nt] = MFMA(a2, bf[2][nt], acc[nt]);
            acc[nt] = MFMA(a3, bf[3][nt], acc[nt]);
        }
#pragma unroll
        for (int i = 0; i < 4; ++i) {
            const int nr = n0 + quad * 4 + i;
#pragma unroll
            for (int nt = 0; nt < 4; ++nt)
                h[(size_t)nr * 64 + nt * 16 + col] = fast_tanh(acc[nt][i]);
        }
    }
}

// ---------- K8 (new): elementwise edge finish: e = tanh(q3[e] + p1[src] + p2[dst]) ----------
__global__ __launch_bounds__(256) void edge_final(
    const unsigned* __restrict__ q3, const float* __restrict__ p1,
    const float* __restrict__ p2, const int* __restrict__ src_idx,
    const int* __restrict__ dst_idx, float* __restrict__ e_out) {
    const int stride = gridDim.x * 256;
    for (int tid = blockIdx.x * 256 + threadIdx.x; tid < NEDGES * 16; tid += stride) {
        const int e = tid >> 4, col = tid & 15;
        const int src = src_idx[e];
        const int dst = dst_idx[e];
        const unsigned q = q3[tid];
        const float2 g1 = *(const float2*)(p1 + (size_t)src * 32 + (col << 1));
        const float2 g2 = *(const float2*)(p2 + (size_t)dst * 32 + (col << 1));
        e_out[(size_t)e * 32 + col]      = fast_tanh(bf16_lo(q) + g1.x + g2.x);
        e_out[(size_t)e * 32 + 16 + col] = fast_tanh(bf16_hi(q) + g1.y + g2.y);
    }
}

// ---------- K8 (fallback, ws too small): edge MLP with MFMA ----------
struct EBuf { ABu a4; float2 g1[4]; float2 g2[4]; };

__device__ __forceinline__ void edge_load(
    int t, int col, int quad,
    const float* __restrict__ edge_feat,
    const float* __restrict__ p1, const float* __restrict__ p2,
    const int* __restrict__ src_idx, const int* __restrict__ dst_idx, EBuf& b) {
    const int e0 = t << 4;
    const int4 s4 = *(const int4*)(src_idx + e0 + (quad << 2));
    const int4 d4 = *(const int4*)(dst_idx + e0 + (quad << 2));
    b.a4 = make_afrag(edge_feat + (size_t)(e0 + col) * 32 + (quad << 3));
    b.g1[0] = *(const float2*)(p1 + (size_t)s4.x * 32 + (col << 1));
    b.g1[1] = *(const float2*)(p1 + (size_t)s4.y * 32 + (col << 1));
    b.g1[2] = *(const float2*)(p1 + (size_t)s4.z * 32 + (col << 1));
    b.g1[3] = *(const float2*)(p1 + (size_t)s4.w * 32 + (col << 1));
    b.g2[0] = *(const float2*)(p2 + (size_t)d4.x * 32 + (col << 1));
    b.g2[1] = *(const float2*)(p2 + (size_t)d4.y * 32 + (col << 1));
    b.g2[2] = *(const float2*)(p2 + (size_t)d4.z * 32 + (col << 1));
    b.g2[3] = *(const float2*)(p2 + (size_t)d4.w * 32 + (col << 1));
}

__device__ __forceinline__ void edge_comp(
    int t, int col, int quad, const ABu (&bf)[2],
    const EBuf& b, float* __restrict__ e_out) {
    f32x4 acc[2];
#pragma unroll
    for (int nt = 0; nt < 2; ++nt) acc[nt] = (f32x4){0.f, 0.f, 0.f, 0.f};
#pragma unroll
    for (int nt = 0; nt < 2; ++nt) acc[nt] = MFMA(b.a4, bf[nt], acc[nt]);
    const int e0 = t << 4;
#pragma unroll
    for (int i = 0; i < 4; ++i) {
        const int er = e0 + (quad << 2) + i;
        e_out[(size_t)er * 32 + col] = fast_tanh(acc[0][i] + b.g1[i].x + b.g2[i].x);
        e_out[(size_t)er * 32 + 16 + col] = fast_tanh(acc[1][i] + b.g1[i].y + b.g2[i].y);
    }
}

__global__ __launch_bounds__(256) void edge_update(
    const float* __restrict__ edge_feat, const float* __restrict__ w3,
    const float* __restrict__ p1, const float* __restrict__ p2,
    const int* __restrict__ src_idx, const int* __restrict__ dst_idx,
    float* __restrict__ e_out) {
    __shared__ __align__(16) unsigned wl[16 * 32];  // 2 KB: W3 (32x32) packed
    stage_w<16, 32>(w3, wl);
    __syncthreads();

    const int lane = threadIdx.x & 63, wave = threadIdx.x >> 6;
    const int col = lane & 15, quad = lane >> 4;

    ABu bf[2];
#pragma unroll
    for (int nt = 0; nt < 2; ++nt)
        bf[nt] = make_bfrag_u<32>(&wl[(quad << 2) * 32 + nt * 16 + col]);

    const int nw = gridDim.x << 2;
    int t = (blockIdx.x << 2) + wave;
    if (t >= NTILE_E) return;
    EBuf A, B;
    edge_load(t, col, quad, edge_feat, p1, p2, src_idx, dst_idx, A);
    for (;;) {
        const int t2 = t + nw;
        if (t2 < NTILE_E)
            edge_load(t2, col, quad, edge_feat, p1, p2, src_idx, dst_idx, B);
        edge_comp(t, col, quad, bf, A, e_out);
        if (t2 >= NTILE_E) return;
        const int t3 = t2 + nw;
        if (t3 < NTILE_E)
            edge_load(t3, col, quad, edge_feat, p1, p2, src_idx, dst_idx, A);
        edge_comp(t2, col, quad, bf, B, e_out);
        if (t3 >= NTILE_E) return;
        t = t3;
    }
}

extern "C" void kernel_launch(void* const* d_in, const int* in_sizes, int n_in,
                              void* d_out, int out_size, void* d_ws, size_t ws_size,
                              hipStream_t stream) {
    const float* feat      = (const float*)d_in[0];
    const float* edge_feat = (const float*)d_in[1];
    const float* w_msg     = (const float*)d_in[2];
    const float* b_msg     = (const float*)d_in[3];
    const float* w_node    = (const float*)d_in[4];
    const float* b_node    = (const float*)d_in[5];
    const float* w_edge    = (const float*)d_in[6];
    const float* b_edge    = (const float*)d_in[7];
    const int*   src_idx   = (const int*)d_in[8];
    const int*   dst_idx   = (const int*)d_in[9];

    float* h = (float*)d_out;                            // [50000,64]
    float* e = (float*)d_out + (size_t)NNODES * 64;      // [800000,32]
    unsigned* m = (unsigned*)e;  // bf16 m matrix (dst-sorted) in the not-yet-written e region
    float* projm = h;            // proj_msg lives in h region until gather overwrites it

    int* cnt  = (int*)d_ws;          // [NPAD]
    int* off  = cnt + NPAD;          // [NPAD]  exclusive starts (never mutated after scan)
    int* btot = off + NPAD;          // [256]
    int* rank = btot + 256;          // [NEDGES] rank -> absolute row (after rows_kernel)
    float* p1 = (float*)(rank + NEDGES);   // [NNODES*32] feat @ W1 + b_edge
    float* p2 = p1 + (size_t)NNODES * 32;  // [NNODES*32] h @ W2
    unsigned* q3 = (unsigned*)(p2 + (size_t)NNODES * 32);  // [NEDGES*16] bf16x2 ef@W3

    const size_t ws_need = (size_t)NPAD * 8 + 1024 + (size_t)NEDGES * 4 +
                           (size_t)NNODES * 32 * 8 + (size_t)NEDGES * 16 * 4;
    const bool big_ws = ws_size >= ws_need;

    hipMemsetAsync(cnt, 0, NPAD * sizeof(int), stream);
    hipMemsetAsync(btot, 0, 256 * sizeof(int), stream);

    hist_kernel<<<(NEDGES / 4 + 255) / 256, 256, 0, stream>>>(dst_idx, cnt, rank);
    scan1<<<NPAD / 256, 256, 0, stream>>>(cnt, off, btot);
    scan2<<<1, 256, 0, stream>>>(btot);
    scan3<<<NPAD / 256, 256, 0, stream>>>(off, btot);
    rows_kernel<<<(NEDGES / 4 + 255) / 256, 256, 0, stream>>>(dst_idx, off, rank);
    // projm = feat @ w_msg[0:64] + b_msg ; p1 = feat @ w_edge[0:64] + b_edge  (one feat pass)
    proj2_kernel<<<256, 256, 0, stream>>>(feat, w_msg, b_msg, w_edge, b_edge, projm, p1);
    if (big_ws) {
        msg_kernel<true><<<2500, 256, 0, stream>>>(edge_feat, w_msg + 64 * 64,
                                                   w_edge + 128 * 32, src_idx, rank,
                                                   projm, m, q3);
    } else {
        msg_kernel<false><<<2500, 256, 0, stream>>>(edge_feat, w_msg + 64 * 64,
                                                    nullptr, src_idx, rank,
                                                    projm, m, nullptr);
    }
    gather_kernel<<<NNODES / 4, 256, 0, stream>>>(m, off, cnt, h);
    node_update<<<512, 256, 0, stream>>>(feat, w_node, b_node, h);
    proj_kernel<2, 2><<<256, 256, 0, stream>>>(h, w_edge + 64 * 32, nullptr, p2);
    if (big_ws) {
        edge_final<<<4096, 256, 0, stream>>>(q3, p1, p2, src_idx, dst_idx, e);
    } else {
        edge_update<<<2500, 256, 0, stream>>>(edge_feat, w_edge + 128 * 32,
                                              p1, p2, src_idx, dst_idx, e);
    }
}

// Round 6
// 379.355 us; speedup vs baseline: 1.0522x; 1.0522x over previous
//
#include <hip/hip_runtime.h>

#define NNODES 50000
#define NEDGES 800000
#define NPAD   50176          // 196*256, padded bin count for the scan
#define NTILE_E (NEDGES / 16) // 50000 edge tiles
#define NTILE_N (NNODES / 16) // 3125 node tiles

typedef __attribute__((ext_vector_type(8))) short bf16x8;   // 8 bf16 = 4 VGPRs
typedef __attribute__((ext_vector_type(4))) float f32x4;

union ABu { bf16x8 v; uint4 u; };

// tanh(x) = 1 - 2/(exp(2x)+1); saturates cleanly, no NaN.
__device__ __forceinline__ float fast_tanh(float x) {
    float e = __expf(2.0f * x);
    return 1.0f - 2.0f * __builtin_amdgcn_rcpf(e + 1.0f);
}

// RNE pack two f32 -> bf16x2
__device__ __forceinline__ unsigned pk_rne(float x, float y) {
    unsigned a = __float_as_uint(x), b = __float_as_uint(y);
    a = (a + 0x7fffu + ((a >> 16) & 1u)) >> 16;
    b = (b + 0x7fffu + ((b >> 16) & 1u)) >> 16;
    return a | (b << 16);
}
// truncating pack (1 v_perm): dst = {a[31:16], b[31:16]}
__device__ __forceinline__ unsigned pk_tr(float a, float b) {
    return __builtin_amdgcn_perm(__float_as_uint(b), __float_as_uint(a), 0x07060302);
}
__device__ __forceinline__ float bf16_lo(unsigned u) { return __uint_as_float(u << 16); }
__device__ __forceinline__ float bf16_hi(unsigned u) { return __uint_as_float(u & 0xffff0000u); }

// A-fragment (lane holds A[m=lane&15][k=quad*8+j]) from 8 consecutive f32
__device__ __forceinline__ ABu make_afrag(const float* p) {
    float4 a = ((const float4*)p)[0];
    float4 b = ((const float4*)p)[1];
    ABu r;
    r.u.x = pk_tr(a.x, a.y); r.u.y = pk_tr(a.z, a.w);
    r.u.z = pk_tr(b.x, b.y); r.u.w = pk_tr(b.z, b.w);
    return r;
}

// B-fragment from bf16x2-packed LDS: wl_u[kp*LDN + n], kp = k/2
template <int LDN>
__device__ __forceinline__ ABu make_bfrag_u(const unsigned* wp) {
    ABu r;
    r.u.x = wp[0 * LDN]; r.u.y = wp[1 * LDN];
    r.u.z = wp[2 * LDN]; r.u.w = wp[3 * LDN];
    return r;
}

// stage f32 weight [K][N] -> packed bf16 pairs [K/2][N] in LDS
template <int KH, int N>
__device__ __forceinline__ void stage_w(const float* __restrict__ w, unsigned* wl_u) {
    for (int i = threadIdx.x; i < KH * N; i += 256) {
        const int kp = i / N, n = i % N;  // N = 32/64 -> shifts
        wl_u[i] = pk_rne(w[(2 * kp) * N + n], w[(2 * kp + 1) * N + n]);
    }
}

#define MFMA(a, b, c) __builtin_amdgcn_mfma_f32_16x16x32_bf16((a).v, (b).v, (c), 0, 0, 0)

// ---------- K0: dst histogram + per-edge rank within dst segment ----------
__global__ __launch_bounds__(256) void hist_kernel(const int* __restrict__ dst_idx,
                                                   int* __restrict__ cnt,
                                                   int* __restrict__ rank) {
    const int base = (blockIdx.x * 256 + threadIdx.x) * 4;
    if (base + 4 <= NEDGES) {
        int4 d = *(const int4*)(dst_idx + base);
        int4 r;
        r.x = atomicAdd(&cnt[d.x], 1);
        r.y = atomicAdd(&cnt[d.y], 1);
        r.z = atomicAdd(&cnt[d.z], 1);
        r.w = atomicAdd(&cnt[d.w], 1);
        *(int4*)(rank + base) = r;
    }
}

// ---------- K1/K2: exclusive scan of 50176 bins (2 kernels) ----------
__global__ __launch_bounds__(256) void scan1(const int* __restrict__ cnt,
                                             int* __restrict__ off,
                                             int* __restrict__ btot) {
    __shared__ int s[256];
    const int tid = threadIdx.x;
    const int g = blockIdx.x * 256 + tid;
    const int own = cnt[g];
    s[tid] = own;
    __syncthreads();
    for (int o = 1; o < 256; o <<= 1) {
        int v = (tid >= o) ? s[tid - o] : 0;
        __syncthreads();
        s[tid] += v;
        __syncthreads();
    }
    off[g] = s[tid] - own;
    if (tid == 255) btot[blockIdx.x] = s[255];
}

// each block redundantly scans btot[256] in LDS, then adds its exclusive prefix
__global__ __launch_bounds__(256) void scan3b(int* __restrict__ off,
                                              const int* __restrict__ btot) {
    __shared__ int s[256];
    const int tid = threadIdx.x;
    s[tid] = btot[tid];
    __syncthreads();
    for (int o = 1; o < 256; o <<= 1) {
        int v = (tid >= o) ? s[tid - o] : 0;
        __syncthreads();
        s[tid] += v;
        __syncthreads();
    }
    const int add = (blockIdx.x == 0) ? 0 : s[blockIdx.x - 1];  // exclusive prefix
    off[blockIdx.x * 256 + tid] += add;
}

// ---------- K3: fold rank -> absolute row: rank[e] += off[dst[e]] (in place) ----------
__global__ __launch_bounds__(256) void rows_kernel(const int* __restrict__ dst_idx,
                                                   const int* __restrict__ off,
                                                   int* __restrict__ rank) {
    const int base = (blockIdx.x * 256 + threadIdx.x) * 4;
    if (base + 4 <= NEDGES) {
        int4 d = *(const int4*)(dst_idx + base);
        int4 r = *(const int4*)(rank + base);
        r.x += off[d.x];
        r.y += off[d.y];
        r.z += off[d.z];
        r.w += off[d.w];
        *(int4*)(rank + base) = r;
    }
}

// ---------- proj2: fused per-node GEMM: projm = feat@Wm + bm ; p1 = feat@We1 + be ----------
// projm storage NT=4 swizzle: projm[n*64 + col*4 + nt] = logical col nt*16+col.
// p1 storage NT=2 swizzle:    p1[n*32 + col*2 + nt]    = logical col nt*16+col.
__global__ __launch_bounds__(256) void proj2_kernel(
    const float* __restrict__ feat,
    const float* __restrict__ w_m, const float* __restrict__ b_m,
    const float* __restrict__ w_e, const float* __restrict__ b_e,
    float* __restrict__ projm, float* __restrict__ p1) {
    __shared__ __align__(16) unsigned wlm[32 * 64];  // 8 KB
    __shared__ __align__(16) unsigned wle[32 * 32];  // 4 KB
    stage_w<32, 64>(w_m, wlm);
    stage_w<32, 32>(w_e, wle);
    __syncthreads();

    const int lane = threadIdx.x & 63, wave = threadIdx.x >> 6;
    const int col = lane & 15, quad = lane >> 4;

    ABu bfm[2][4], bfe[2][2];
#pragma unroll
    for (int kc = 0; kc < 2; ++kc) {
#pragma unroll
        for (int nt = 0; nt < 4; ++nt)
            bfm[kc][nt] = make_bfrag_u<64>(&wlm[(kc * 16 + (quad << 2)) * 64 + nt * 16 + col]);
#pragma unroll
        for (int nt = 0; nt < 2; ++nt)
            bfe[kc][nt] = make_bfrag_u<32>(&wle[(kc * 16 + (quad << 2)) * 32 + nt * 16 + col]);
    }

    float bim[4], bie[2];
#pragma unroll
    for (int nt = 0; nt < 4; ++nt) bim[nt] = b_m[nt * 16 + col];
#pragma unroll
    for (int nt = 0; nt < 2; ++nt) bie[nt] = b_e[nt * 16 + col];

    const int nw = gridDim.x << 2;
    for (int t = (blockIdx.x << 2) + wave; t < NTILE_N; t += nw) {
        const int n0 = t << 4;
        const int n = n0 + col;
        ABu a0 = make_afrag(feat + (size_t)n * 64 + (quad << 3));
        ABu a1 = make_afrag(feat + (size_t)n * 64 + 32 + (quad << 3));

        f32x4 accm[4], acce[2];
#pragma unroll
        for (int nt = 0; nt < 4; ++nt)
            accm[nt] = (f32x4){bim[nt], bim[nt], bim[nt], bim[nt]};
#pragma unroll
        for (int nt = 0; nt < 2; ++nt)
            acce[nt] = (f32x4){bie[nt], bie[nt], bie[nt], bie[nt]};
#pragma unroll
        for (int nt = 0; nt < 4; ++nt) {
            accm[nt] = MFMA(a0, bfm[0][nt], accm[nt]);
            accm[nt] = MFMA(a1, bfm[1][nt], accm[nt]);
        }
#pragma unroll
        for (int nt = 0; nt < 2; ++nt) {
            acce[nt] = MFMA(a0, bfe[0][nt], acce[nt]);
            acce[nt] = MFMA(a1, bfe[1][nt], acce[nt]);
        }
#pragma unroll
        for (int i = 0; i < 4; ++i) {
            const int nr = n0 + (quad << 2) + i;
            float4 om = {accm[0][i], accm[1][i], accm[2][i], accm[3][i]};
            *(float4*)(projm + (size_t)nr * 64 + (col << 2)) = om;
            float2 oe = {acce[0][i], acce[1][i]};
            *(float2*)(p1 + (size_t)nr * 32 + (col << 1)) = oe;
        }
    }
}

// ---------- K4: message = tanh(projm[src] + ef @ W_bot), dst-sorted write ----------
// m storage (uint index s in [0,32) per edge): s = col*2 + w;
//   w=0 -> logical cols (col, col+16), w=1 -> (col+32, col+48)
struct MsgBuf { ABu a2; float4 f4[4]; int4 rows; };

__device__ __forceinline__ void msg_load(
    int t, int col, int quad,
    const float* __restrict__ edge_feat, const float* __restrict__ projm,
    const int* __restrict__ src_idx, const int* __restrict__ rows, MsgBuf& b) {
    const int e0 = t << 4;
    const int4 s4 = *(const int4*)(src_idx + e0 + (quad << 2));
    b.rows = *(const int4*)(rows + e0 + (quad << 2));
    b.a2 = make_afrag(edge_feat + (size_t)(e0 + col) * 32 + (quad << 3));
    b.f4[0] = *(const float4*)(projm + (size_t)s4.x * 64 + (col << 2));
    b.f4[1] = *(const float4*)(projm + (size_t)s4.y * 64 + (col << 2));
    b.f4[2] = *(const float4*)(projm + (size_t)s4.z * 64 + (col << 2));
    b.f4[3] = *(const float4*)(projm + (size_t)s4.w * 64 + (col << 2));
}

__device__ __forceinline__ void msg_comp(
    int col, const ABu (&bf)[4], const MsgBuf& b, unsigned* __restrict__ m_out) {
    f32x4 acc[4];
#pragma unroll
    for (int nt = 0; nt < 4; ++nt) acc[nt] = (f32x4){0.f, 0.f, 0.f, 0.f};
#pragma unroll
    for (int nt = 0; nt < 4; ++nt) acc[nt] = MFMA(b.a2, bf[nt], acc[nt]);
    const int rw[4] = {b.rows.x, b.rows.y, b.rows.z, b.rows.w};
#pragma unroll
    for (int i = 0; i < 4; ++i) {
        uint2 o;
        o.x = pk_rne(fast_tanh(acc[0][i] + b.f4[i].x), fast_tanh(acc[1][i] + b.f4[i].y));
        o.y = pk_rne(fast_tanh(acc[2][i] + b.f4[i].z), fast_tanh(acc[3][i] + b.f4[i].w));
        *(uint2*)(m_out + (size_t)rw[i] * 32 + (col << 1)) = o;  // 128B/quad contiguous
    }
}

__global__ __launch_bounds__(256) void msg_kernel(
    const float* __restrict__ edge_feat, const float* __restrict__ w_bot,
    const int* __restrict__ src_idx, const int* __restrict__ rows,
    const float* __restrict__ projm, unsigned* __restrict__ m_out) {
    __shared__ __align__(16) unsigned wl[16 * 64];  // 4 KB: W_bot rows 0..31 packed
    stage_w<16, 64>(w_bot, wl);
    __syncthreads();

    const int lane = threadIdx.x & 63, wave = threadIdx.x >> 6;
    const int col = lane & 15, quad = lane >> 4;

    ABu bf[4];
#pragma unroll
    for (int nt = 0; nt < 4; ++nt)
        bf[nt] = make_bfrag_u<64>(&wl[(quad << 2) * 64 + nt * 16 + col]);

    const int nw = gridDim.x << 2;
    int t = (blockIdx.x << 2) + wave;
    if (t >= NTILE_E) return;
    MsgBuf A, B;
    msg_load(t, col, quad, edge_feat, projm, src_idx, rows, A);
    for (;;) {
        const int t2 = t + nw;
        if (t2 < NTILE_E)
            msg_load(t2, col, quad, edge_feat, projm, src_idx, rows, B);
        msg_comp(col, bf, A, m_out);
        if (t2 >= NTILE_E) return;
        const int t3 = t2 + nw;
        if (t3 < NTILE_E)
            msg_load(t3, col, quad, edge_feat, projm, src_idx, rows, A);
        msg_comp(col, bf, B, m_out);
        if (t3 >= NTILE_E) return;
        t = t3;
    }
}

// storage k -> logical w_node row (undo the m/neigh swizzle) for k<64
__device__ __forceinline__ int mapk(int ks) {
    return ks < 64 ? ((ks >> 2) + ((ks >> 1) & 1) * 32 + (ks & 1) * 16) : ks;
}

// ---------- K5 (fused): segmented mean -> node MLP -> h AND p2 = h@W2 ----------
// One wave owns one 16-node tile. Lane (col,quad):
//   - streams m rows of node n0+col (full 128B lines across the 4 quads x 2 halves),
//     accumulating the MFMA A-fragment (storage k order) directly -> no neigh pass.
//   - node MFMA (wl: mapk-packed W_node; k storage order for neigh, logical for feat).
//   - h tile transposed in per-wave padded LDS -> A-frags -> p2 MFMA (wl2: W2 packed).
__global__ __launch_bounds__(256) void gnode_kernel(
    const float* __restrict__ feat, const unsigned* __restrict__ m,
    const int* __restrict__ off, const int* __restrict__ cnt,
    const float* __restrict__ w_node, const float* __restrict__ b_node,
    const float* __restrict__ w2,
    float* __restrict__ h, float* __restrict__ p2) {
    __shared__ __align__(16) unsigned wl[64 * 64];   // 16 KB: W_node mapk-packed
    __shared__ __align__(16) unsigned wl2[32 * 32];  // 4 KB: W2 (64x32) packed
    __shared__ float tr[4][16 * 68];                 // per-wave h transpose, pad 68

    for (int i = threadIdx.x; i < 64 * 64; i += 256) {
        const int kp = i >> 6, n = i & 63;
        wl[i] = pk_rne(w_node[mapk(2 * kp) * 64 + n], w_node[mapk(2 * kp + 1) * 64 + n]);
    }
    stage_w<32, 32>(w2, wl2);
    __syncthreads();

    const int lane = threadIdx.x & 63, wave = threadIdx.x >> 6;
    const int col = lane & 15, quad = lane >> 4;

    int t = blockIdx.x * 4 + wave;
    if (t > NTILE_N - 1) t = NTILE_N - 1;  // clamp (duplicate tile is idempotent; keeps barriers safe)
    const int n0 = t << 4;
    const int n = n0 + col;
    const int c = cnt[n];
    const int o = off[n];

    float s0[8], s1[8];
#pragma unroll
    for (int j = 0; j < 8; ++j) { s0[j] = 0.f; s1[j] = 0.f; }
    for (int r = 0; r < c; ++r) {
        const unsigned* rp = m + (size_t)(o + r) * 32;
        const uint4 u0 = *(const uint4*)(rp + (quad << 2));
        const uint4 u1 = *(const uint4*)(rp + 16 + (quad << 2));
        s0[0] += bf16_lo(u0.x); s0[1] += bf16_hi(u0.x);
        s0[2] += bf16_lo(u0.y); s0[3] += bf16_hi(u0.y);
        s0[4] += bf16_lo(u0.z); s0[5] += bf16_hi(u0.z);
        s0[6] += bf16_lo(u0.w); s0[7] += bf16_hi(u0.w);
        s1[0] += bf16_lo(u1.x); s1[1] += bf16_hi(u1.x);
        s1[2] += bf16_lo(u1.y); s1[3] += bf16_hi(u1.y);
        s1[4] += bf16_lo(u1.z); s1[5] += bf16_hi(u1.z);
        s1[6] += bf16_lo(u1.w); s1[7] += bf16_hi(u1.w);
    }
    const float inv = __builtin_amdgcn_rcpf((float)max(c, 1));
    ABu a0, a1;
    a0.u.x = pk_tr(s0[0] * inv, s0[1] * inv); a0.u.y = pk_tr(s0[2] * inv, s0[3] * inv);
    a0.u.z = pk_tr(s0[4] * inv, s0[5] * inv); a0.u.w = pk_tr(s0[6] * inv, s0[7] * inv);
    a1.u.x = pk_tr(s1[0] * inv, s1[1] * inv); a1.u.y = pk_tr(s1[2] * inv, s1[3] * inv);
    a1.u.z = pk_tr(s1[4] * inv, s1[5] * inv); a1.u.w = pk_tr(s1[6] * inv, s1[7] * inv);
    const ABu a2 = make_afrag(feat + (size_t)n * 64 + (quad << 3));
    const ABu a3 = make_afrag(feat + (size_t)n * 64 + 32 + (quad << 3));

    f32x4 acc[4];
#pragma unroll
    for (int nt = 0; nt < 4; ++nt) {
        const float bi = b_node[nt * 16 + col];
        acc[nt] = (f32x4){bi, bi, bi, bi};
    }
#pragma unroll
    for (int nt = 0; nt < 4; ++nt) {
        acc[nt] = MFMA(a0, make_bfrag_u<64>(&wl[((quad << 2)) * 64 + nt * 16 + col]), acc[nt]);
        acc[nt] = MFMA(a1, make_bfrag_u<64>(&wl[(16 + (quad << 2)) * 64 + nt * 16 + col]), acc[nt]);
        acc[nt] = MFMA(a2, make_bfrag_u<64>(&wl[(32 + (quad << 2)) * 64 + nt * 16 + col]), acc[nt]);
        acc[nt] = MFMA(a3, make_bfrag_u<64>(&wl[(48 + (quad << 2)) * 64 + nt * 16 + col]), acc[nt]);
    }

    float* trw = tr[wave];
#pragma unroll
    for (int i = 0; i < 4; ++i) {
        const int nr = n0 + (quad << 2) + i;
#pragma unroll
        for (int nt = 0; nt < 4; ++nt) {
            const float ht = fast_tanh(acc[nt][i]);
            h[(size_t)nr * 64 + nt * 16 + col] = ht;
            trw[((quad << 2) + i) * 68 + nt * 16 + col] = ht;  // logical layout
        }
    }
    __syncthreads();  // tr visible (cross-lane within wave; all waves participate)

    // transposed read: node = col, k = quad*8+j (logical); pk_tr matches make_afrag numerics
    float f[8], g[8];
#pragma unroll
    for (int j = 0; j < 8; ++j) {
        f[j] = trw[col * 68 + (quad << 3) + j];
        g[j] = trw[col * 68 + 32 + (quad << 3) + j];
    }
    ABu aT0, aT1;
    aT0.u.x = pk_tr(f[0], f[1]); aT0.u.y = pk_tr(f[2], f[3]);
    aT0.u.z = pk_tr(f[4], f[5]); aT0.u.w = pk_tr(f[6], f[7]);
    aT1.u.x = pk_tr(g[0], g[1]); aT1.u.y = pk_tr(g[2], g[3]);
    aT1.u.z = pk_tr(g[4], g[5]); aT1.u.w = pk_tr(g[6], g[7]);

    f32x4 acc2[2];
#pragma unroll
    for (int nt = 0; nt < 2; ++nt) acc2[nt] = (f32x4){0.f, 0.f, 0.f, 0.f};
#pragma unroll
    for (int nt = 0; nt < 2; ++nt) {
        acc2[nt] = MFMA(aT0, make_bfrag_u<32>(&wl2[((quad << 2)) * 32 + nt * 16 + col]), acc2[nt]);
        acc2[nt] = MFMA(aT1, make_bfrag_u<32>(&wl2[(16 + (quad << 2)) * 32 + nt * 16 + col]), acc2[nt]);
    }
#pragma unroll
    for (int i = 0; i < 4; ++i) {
        const int nr = n0 + (quad << 2) + i;
        float2 o2 = {acc2[0][i], acc2[1][i]};
        *(float2*)(p2 + (size_t)nr * 32 + (col << 1)) = o2;  // p1/p2 swizzled storage
    }
}

// ---------- K6: edge out = tanh(p1[src] + p2[dst] + edge_feat @ W3) ----------
struct EBuf { ABu a4; float2 g1[4]; float2 g2[4]; };

__device__ __forceinline__ void edge_load(
    int t, int col, int quad,
    const float* __restrict__ edge_feat,
    const float* __restrict__ p1, const float* __restrict__ p2,
    const int* __restrict__ src_idx, const int* __restrict__ dst_idx, EBuf& b) {
    const int e0 = t << 4;
    const int4 s4 = *(const int4*)(src_idx + e0 + (quad << 2));
    const int4 d4 = *(const int4*)(dst_idx + e0 + (quad << 2));
    b.a4 = make_afrag(edge_feat + (size_t)(e0 + col) * 32 + (quad << 3));
    b.g1[0] = *(const float2*)(p1 + (size_t)s4.x * 32 + (col << 1));
    b.g1[1] = *(const float2*)(p1 + (size_t)s4.y * 32 + (col << 1));
    b.g1[2] = *(const float2*)(p1 + (size_t)s4.z * 32 + (col << 1));
    b.g1[3] = *(const float2*)(p1 + (size_t)s4.w * 32 + (col << 1));
    b.g2[0] = *(const float2*)(p2 + (size_t)d4.x * 32 + (col << 1));
    b.g2[1] = *(const float2*)(p2 + (size_t)d4.y * 32 + (col << 1));
    b.g2[2] = *(const float2*)(p2 + (size_t)d4.z * 32 + (col << 1));
    b.g2[3] = *(const float2*)(p2 + (size_t)d4.w * 32 + (col << 1));
}

__device__ __forceinline__ void edge_comp(
    int t, int col, int quad, const ABu (&bf)[2],
    const EBuf& b, float* __restrict__ e_out) {
    f32x4 acc[2];
#pragma unroll
    for (int nt = 0; nt < 2; ++nt) acc[nt] = (f32x4){0.f, 0.f, 0.f, 0.f};
#pragma unroll
    for (int nt = 0; nt < 2; ++nt) acc[nt] = MFMA(b.a4, bf[nt], acc[nt]);
    const int e0 = t << 4;
#pragma unroll
    for (int i = 0; i < 4; ++i) {
        const int er = e0 + (quad << 2) + i;
        e_out[(size_t)er * 32 + col] = fast_tanh(acc[0][i] + b.g1[i].x + b.g2[i].x);
        e_out[(size_t)er * 32 + 16 + col] = fast_tanh(acc[1][i] + b.g1[i].y + b.g2[i].y);
    }
}

__global__ __launch_bounds__(256) void edge_update(
    const float* __restrict__ edge_feat, const float* __restrict__ w3,
    const float* __restrict__ p1, const float* __restrict__ p2,
    const int* __restrict__ src_idx, const int* __restrict__ dst_idx,
    float* __restrict__ e_out) {
    __shared__ __align__(16) unsigned wl[16 * 32];  // 2 KB: W3 (32x32) packed
    stage_w<16, 32>(w3, wl);
    __syncthreads();

    const int lane = threadIdx.x & 63, wave = threadIdx.x >> 6;
    const int col = lane & 15, quad = lane >> 4;

    ABu bf[2];
#pragma unroll
    for (int nt = 0; nt < 2; ++nt)
        bf[nt] = make_bfrag_u<32>(&wl[(quad << 2) * 32 + nt * 16 + col]);

    const int nw = gridDim.x << 2;
    int t = (blockIdx.x << 2) + wave;
    if (t >= NTILE_E) return;
    EBuf A, B;
    edge_load(t, col, quad, edge_feat, p1, p2, src_idx, dst_idx, A);
    for (;;) {
        const int t2 = t + nw;
        if (t2 < NTILE_E)
            edge_load(t2, col, quad, edge_feat, p1, p2, src_idx, dst_idx, B);
        edge_comp(t, col, quad, bf, A, e_out);
        if (t2 >= NTILE_E) return;
        const int t3 = t2 + nw;
        if (t3 < NTILE_E)
            edge_load(t3, col, quad, edge_feat, p1, p2, src_idx, dst_idx, A);
        edge_comp(t2, col, quad, bf, B, e_out);
        if (t3 >= NTILE_E) return;
        t = t3;
    }
}

extern "C" void kernel_launch(void* const* d_in, const int* in_sizes, int n_in,
                              void* d_out, int out_size, void* d_ws, size_t ws_size,
                              hipStream_t stream) {
    const float* feat      = (const float*)d_in[0];
    const float* edge_feat = (const float*)d_in[1];
    const float* w_msg     = (const float*)d_in[2];
    const float* b_msg     = (const float*)d_in[3];
    const float* w_node    = (const float*)d_in[4];
    const float* b_node    = (const float*)d_in[5];
    const float* w_edge    = (const float*)d_in[6];
    const float* b_edge    = (const float*)d_in[7];
    const int*   src_idx   = (const int*)d_in[8];
    const int*   dst_idx   = (const int*)d_in[9];

    float* h = (float*)d_out;                            // [50000,64]
    float* e = (float*)d_out + (size_t)NNODES * 64;      // [800000,32]
    unsigned* m = (unsigned*)e;  // bf16 m matrix (dst-sorted) in the not-yet-written e region
    float* projm = h;            // proj_msg lives in h region until gnode overwrites it

    int* cnt  = (int*)d_ws;          // [NPAD]
    int* off  = cnt + NPAD;          // [NPAD]  exclusive starts (never mutated after scan)
    int* btot = off + NPAD;          // [256]
    int* rank = btot + 256;          // [NEDGES] rank -> absolute row (after rows_kernel)
    float* p1 = (float*)(rank + NEDGES);   // [NNODES*32] feat @ W1 + b_edge
    float* p2 = p1 + (size_t)NNODES * 32;  // [NNODES*32] h @ W2

    hipMemsetAsync(cnt, 0, NPAD * sizeof(int), stream);
    hipMemsetAsync(btot, 0, 256 * sizeof(int), stream);

    hist_kernel<<<(NEDGES / 4 + 255) / 256, 256, 0, stream>>>(dst_idx, cnt, rank);
    scan1<<<NPAD / 256, 256, 0, stream>>>(cnt, off, btot);
    scan3b<<<NPAD / 256, 256, 0, stream>>>(off, btot);
    rows_kernel<<<(NEDGES / 4 + 255) / 256, 256, 0, stream>>>(dst_idx, off, rank);
    // projm = feat @ w_msg[0:64] + b_msg ; p1 = feat @ w_edge[0:64] + b_edge  (one feat pass)
    proj2_kernel<<<256, 256, 0, stream>>>(feat, w_msg, b_msg, w_edge, b_edge, projm, p1);
    msg_kernel<<<2500, 256, 0, stream>>>(edge_feat, w_msg + 64 * 64,
                                         src_idx, rank, projm, m);
    // fused: segmented mean + node MLP + p2 = h @ w_edge[64:128]
    gnode_kernel<<<(NTILE_N + 3) / 4, 256, 0, stream>>>(feat, m, off, cnt,
                                                        w_node, b_node,
                                                        w_edge + 64 * 32, h, p2);
    edge_update<<<2500, 256, 0, stream>>>(edge_feat, w_edge + 128 * 32,
                                          p1, p2, src_idx, dst_idx, e);
}